// Round 1
// baseline (189.262 us; speedup 1.0000x reference)
//
#include <hip/hip_runtime.h>
#include <math.h>

// Problem constants (setup_inputs is fixed)
#define BB 2
#define HH 48
#define WW 48
#define DD 24
#define KK 20
#define AA 9
#define TOTAL (HH*WW*DD*AA)   // 497664 anchors per batch (natural order i = ((h*W+w)*D+d)*A+a)
#define SPAT (HH*WW*DD)       // 55296
#define OUT0N (BB*TOTAL)      // 995328, output-0 order t = (((b*A+a)*H+h)*W+w)*D+d
#define CH 54                 // 6*A channels for outputs 1..3
#define NB 4096               // rand-value histogram buckets
#define CAP 4096              // tie-bucket list capacity
#define FG_QUOTA 128
#define RPN_B 256
#define STRIDE_F 16.0f

// Workspace layout (4-byte words). ~4.1 MB total.
#define O_ARGMAX 0
#define O_GTMAX  (OUT0N)                 // B*K encoded float maxima
#define O_HIST   (O_GTMAX + BB*KK)       // 4 flavors (fg b0, fg b1, bg b0, bg b1) * NB
#define O_CUT    (O_HIST + 4*NB)         // 4 flavors * 3 ints: cut_bucket, rank_base, quota
#define O_TIEN   (O_CUT + 12)            // 4 tie-list counters
#define O_TIE    (O_TIEN + 4)            // 4 * CAP anchor indices
#define O_W      (O_TIE + 4*CAP)         // scalar weight 1/num_examples (batch B-1)

// Monotone float<->uint encoding so unsigned atomicMax == float max (exact).
__device__ __forceinline__ unsigned enc_f(float f){
  unsigned u = __float_as_uint(f);
  return (u & 0x80000000u) ? ~u : (u | 0x80000000u);
}
__device__ __forceinline__ float dec_f(unsigned u){
  return (u & 0x80000000u) ? __uint_as_float(u & 0x7FFFFFFFu) : __uint_as_float(~u);
}
#define ENC_NEG1 0x407FFFFFu  // enc(-1.0f)

// IoU exactly as reference. fp contract OFF so the two call sites (k_gtmax,
// k_label) produce bit-identical values -> tie detection (==) is exact.
__device__ __forceinline__ float iou6(float ax1,float ay1,float ax2,float ay2,
                                      float az1,float az2, const float* g){
  #pragma clang fp contract(off)
  float aw = ax2-ax1+1.0f, ah = ay2-ay1+1.0f, ad = az2-az1+1.0f;
  float a_area = aw*ah*ad;
  float gw = g[2]-g[0]+1.0f, gh = g[3]-g[1]+1.0f, gd = g[5]-g[4]+1.0f;
  float g_area = gw*gh*gd;
  float iw = fminf(ax2,g[2]) - fmaxf(ax1,g[0]) + 1.0f; iw = fmaxf(iw,0.0f);
  float ih = fminf(ay2,g[3]) - fmaxf(ay1,g[1]) + 1.0f; ih = fmaxf(ih,0.0f);
  float id = fminf(az2,g[5]) - fmaxf(az1,g[4]) + 1.0f; id = fmaxf(id,0.0f);
  float inter = iw*ih*id;
  float ov = inter / (a_area + g_area - inter);
  if (gw==1.0f && gh==1.0f && gd==1.0f) ov = 0.0f;       // gt_zero mask
  if (aw==1.0f && ah==1.0f && ad==1.0f) ov = -1.0f;      // a_zero mask
  return ov;
}

__global__ void k_init(unsigned* __restrict__ ws){
  int t = blockIdx.x*256 + threadIdx.x;
  if (t < 4*NB) ws[O_HIST + t] = 0u;
  if (t < 4)    ws[O_TIEN + t] = 0u;
  if (t < BB*KK) ws[O_GTMAX + t] = ENC_NEG1;
}

// Per-gt max overlap over all anchors (inside-masked). Each thread handles 8
// anchors keeping 20 running maxima in registers; wave shuffle-reduce; LDS
// atomic; one global atomicMax per (block,k).
#define GM_G 8
#define GM_BLK 243  // TOTAL / (256*GM_G)
__global__ void __launch_bounds__(256) k_gtmax(const float* __restrict__ gt,
    const float* __restrict__ anc, const float* __restrict__ imi,
    unsigned* __restrict__ ws){
  __shared__ float s_gt[KK*7];
  __shared__ float s_anc[AA*6];
  __shared__ float s_im[3];
  __shared__ unsigned s_max[KK];
  int tid = threadIdx.x;
  int b = blockIdx.y;
  for (int j=tid; j<KK*7; j+=256) s_gt[j] = gt[b*KK*7 + j];
  for (int j=tid; j<AA*6; j+=256) s_anc[j] = anc[j];
  if (tid<3) s_im[tid] = imi[tid];
  if (tid<KK) s_max[tid] = ENC_NEG1;
  __syncthreads();
  float rmax[KK];
  #pragma unroll
  for (int k=0;k<KK;k++) rmax[k] = -1.0f;
  int i0 = blockIdx.x*256 + tid;
  for (int g=0; g<GM_G; g++){
    int i = i0 + g*(GM_BLK*256);
    if (i >= TOTAL) break;
    int a = i % AA; int s = i / AA;
    int d = s % DD; int s2 = s / DD;
    int w = s2 % WW; int h = s2 / WW;
    float fx = w*STRIDE_F, fy = h*STRIDE_F, fz = d*STRIDE_F;
    float ax1=s_anc[a*6+0]+fx, ay1=s_anc[a*6+1]+fy, ax2=s_anc[a*6+2]+fx;
    float ay2=s_anc[a*6+3]+fy, az1=s_anc[a*6+4]+fz, az2=s_anc[a*6+5]+fz;
    bool inside = (ax1>=0.f)&&(ay1>=0.f)&&(az1>=0.f)&&
                  (ax2<s_im[1])&&(ay2<s_im[0])&&(az2<s_im[2]);
    if (!inside) continue;  // outside -> ov_m = -1 == init, no contribution
    #pragma unroll
    for (int k=0;k<KK;k++)
      rmax[k] = fmaxf(rmax[k], iou6(ax1,ay1,ax2,ay2,az1,az2, &s_gt[k*7]));
  }
  #pragma unroll
  for (int k=0;k<KK;k++){
    float v = rmax[k];
    for (int off=32; off>0; off>>=1) v = fmaxf(v, __shfl_down(v, off, 64));
    if ((tid & 63) == 0) atomicMax(&s_max[k], enc_f(v));
  }
  __syncthreads();
  if (tid < KK) atomicMax(&ws[O_GTMAX + b*KK + tid], s_max[tid]);
}

// Labels (pre-sampling) written straight into out0 (its layout is the (B,A,H,W,D)
// permutation); argmax cached; fg/bg rand histograms built here.
__global__ void __launch_bounds__(256) k_label(const float* __restrict__ gt,
    const float* __restrict__ anc, const float* __restrict__ imi,
    const float* __restrict__ rfg, const float* __restrict__ rbg,
    float* __restrict__ out0, unsigned* __restrict__ ws){
  __shared__ float s_gt[BB*KK*7];
  __shared__ float s_anc[AA*6];
  __shared__ float s_im[3];
  __shared__ float s_gm[BB*KK];
  int tid = threadIdx.x;
  for (int j=tid; j<BB*KK*7; j+=256) s_gt[j] = gt[j];
  for (int j=tid; j<AA*6; j+=256) s_anc[j] = anc[j];
  if (tid<3) s_im[tid] = imi[tid];
  if (tid<BB*KK){ float g = dec_f(ws[O_GTMAX+tid]); if (g==0.0f) g = 1e-5f; s_gm[tid]=g; }
  __syncthreads();
  int t = blockIdx.x*256 + tid;
  if (t >= OUT0N) return;
  int d = t % DD; int r1 = t/DD;
  int w = r1 % WW; int r2 = r1/WW;
  int h = r2 % HH; int r3 = r2/HH;
  int a = r3 % AA; int b = r3/AA;
  int i = ((h*WW+w)*DD + d)*AA + a;       // natural anchor index (rand arrays)
  float fx=w*STRIDE_F, fy=h*STRIDE_F, fz=d*STRIDE_F;
  float ax1=s_anc[a*6+0]+fx, ay1=s_anc[a*6+1]+fy, ax2=s_anc[a*6+2]+fx;
  float ay2=s_anc[a*6+3]+fy, az1=s_anc[a*6+4]+fz, az2=s_anc[a*6+5]+fz;
  bool inside = (ax1>=0.f)&&(ay1>=0.f)&&(az1>=0.f)&&
                (ax2<s_im[1])&&(ay2<s_im[0])&&(az2<s_im[2]);
  float L = -1.0f;
  int am = 0;
  if (inside){
    float mv = -2.0f; bool tie = false;
    #pragma unroll
    for (int k=0;k<KK;k++){
      float ov = iou6(ax1,ay1,ax2,ay2,az1,az2, &s_gt[(b*KK+k)*7]);
      if (ov > mv){ mv = ov; am = k; }        // first-argmax (strict >)
      tie = tie || (ov == s_gm[b*KK+k]);
    }
    if (mv < 0.3f) L = 0.0f;
    if (tie)       L = 1.0f;
    if (mv >= 0.7f) L = 1.0f;
  }
  out0[t] = L;
  ((int*)ws)[O_ARGMAX + t] = am;
  if (L == 1.0f){
    float r = rfg[b*TOTAL + i];
    int bk = min(NB-1, (int)(r*(float)NB));
    atomicAdd(&ws[O_HIST + b*NB + bk], 1u);
  } else if (L == 0.0f){
    float r = rbg[b*TOTAL + i];
    int bk = min(NB-1, (int)(r*(float)NB));
    atomicAdd(&ws[O_HIST + (2+b)*NB + bk], 1u);
  }
}

// One block per flavor: suffix-scan the histogram (descending value order) to
// find the bucket containing rank quota-1. Counts derived from hist sums (no
// single-address atomic counters). Block 3 (bg, b=1) also computes w.
__global__ void __launch_bounds__(256) k_cuts(unsigned* __restrict__ ws){
  int fl = blockIdx.x; int tid = threadIdx.x;
  int b = fl & 1; int isbg = fl >> 1;
  const int CHK = NB/256;  // 16
  __shared__ unsigned ps[256];
  __shared__ unsigned s_fg;
  if (tid == 0) s_fg = 0u;
  __syncthreads();
  unsigned part = 0;                 // own flavor, descending chunk
  int hi = NB - CHK*tid;
  for (int j = hi-CHK; j < hi; j++) part += ws[O_HIST + fl*NB + j];
  if (isbg){
    unsigned pf = 0;                 // fg count of this batch (for quota / w)
    for (int j = tid*CHK; j < (tid+1)*CHK; j++) pf += ws[O_HIST + b*NB + j];
    atomicAdd(&s_fg, pf);
  }
  ps[tid] = part;
  __syncthreads();
  for (int off=1; off<256; off<<=1){
    unsigned v = (tid>=off) ? ps[tid-off] : 0u;
    __syncthreads();
    ps[tid] += v;
    __syncthreads();
  }
  unsigned N = ps[255];
  unsigned excl = ps[tid] - part;    // candidates in buckets above my chunk
  unsigned F = isbg ? s_fg : N;
  int quota = isbg ? (RPN_B - (int)min(F, (unsigned)FG_QUOTA)) : FG_QUOTA;
  if (fl == 3 && tid == 0){          // w uses batch B-1 counts only
    int fgk = min((int)F, FG_QUOTA);
    int bgk = min((int)N, RPN_B - fgk);
    ((float*)ws)[O_W] = 1.0f / (float)(fgk + bgk);
  }
  int* cut = (int*)&ws[O_CUT + fl*3];
  if ((int)N <= quota){
    if (tid==0){ cut[0] = -1; cut[1] = 0; cut[2] = quota; }
    return;
  }
  unsigned cum = excl;
  for (int bk = hi-1; bk >= hi-CHK; bk--){
    unsigned c = ws[O_HIST + fl*NB + bk];
    if (c > 0u && (unsigned)(quota-1) >= cum && (unsigned)(quota-1) < cum + c){
      cut[0] = bk; cut[1] = (int)cum; cut[2] = quota;   // exactly one finder
    }
    cum += c;
  }
}

// Demote candidates in buckets strictly below the cut; collect cut-bucket
// members for exact resolution.
__global__ void __launch_bounds__(256) k_apply(const float* __restrict__ rfg,
    const float* __restrict__ rbg, float* __restrict__ out0,
    unsigned* __restrict__ ws){
  int t = blockIdx.x*256 + threadIdx.x;
  if (t >= OUT0N) return;
  float L = out0[t];
  int isbg;
  if (L == 1.0f) isbg = 0; else if (L == 0.0f) isbg = 1; else return;
  int d = t % DD; int r1=t/DD; int w=r1%WW; int r2=r1/WW;
  int h = r2 % HH; int r3=r2/HH; int a=r3%AA; int b=r3/AA;
  int fl = isbg*2 + b;
  int cutb = ((int*)ws)[O_CUT + fl*3];
  if (cutb < 0) return;              // N <= quota: keep everyone
  int i = ((h*WW+w)*DD + d)*AA + a;
  const float* ra = isbg ? rbg : rfg;
  float r = ra[b*TOTAL + i];
  int bk = min(NB-1, (int)(r*(float)NB));
  if (bk < cutb) out0[t] = -1.0f;
  else if (bk == cutb){
    unsigned pos = atomicAdd(&ws[O_TIEN + fl], 1u);
    if (pos < CAP) ((int*)ws)[O_TIE + fl*CAP + pos] = i;
  }
}

// Exact stable-rank resolution inside the cut bucket: descending value,
// ascending natural index on ties (== jnp stable argsort of -p).
__global__ void __launch_bounds__(256) k_resolve(const float* __restrict__ rfg,
    const float* __restrict__ rbg, float* __restrict__ out0,
    unsigned* __restrict__ ws){
  int fl = blockIdx.x; int tid = threadIdx.x;
  int b = fl & 1; int isbg = fl >> 1;
  int cutb = ((int*)ws)[O_CUT + fl*3];
  if (cutb < 0) return;
  int rank_base = ((int*)ws)[O_CUT + fl*3 + 1];
  int quota     = ((int*)ws)[O_CUT + fl*3 + 2];
  int n = (int)min(ws[O_TIEN + fl], (unsigned)CAP);
  __shared__ float rv[CAP];
  __shared__ int   ri[CAP];
  const float* ra = isbg ? rbg : rfg;
  for (int e=tid; e<n; e+=256){
    int idx = ((int*)ws)[O_TIE + fl*CAP + e];
    ri[e] = idx; rv[e] = ra[b*TOTAL + idx];
  }
  __syncthreads();
  for (int e=tid; e<n; e+=256){
    float re = rv[e]; int ie = ri[e];
    int cnt = 0;
    for (int j=0; j<n; j++){
      float rj = rv[j];
      cnt += (rj > re) || (rj == re && ri[j] < ie);
    }
    if (rank_base + cnt >= quota){
      int a = ie % AA; int s = ie/AA; int d = s%DD; int s2 = s/DD;
      int w = s2 % WW; int h = s2 / WW;
      int o = (((b*AA+a)*HH + h)*WW + w)*DD + d;
      out0[o] = -1.0f;
    }
  }
}

// Final outputs: bbox targets (channel = a*6+c planes), inside weights,
// outside weights. Labels already final in out0.
__global__ void __launch_bounds__(256) k_out(const float* __restrict__ gt,
    const float* __restrict__ anc, const float* __restrict__ imi,
    const float* __restrict__ out0c, float* __restrict__ out,
    const unsigned* __restrict__ ws){
  __shared__ float s_gt[BB*KK*7];
  __shared__ float s_anc[AA*6];
  __shared__ float s_im[3];
  __shared__ float s_w;
  int tid = threadIdx.x;
  for (int j=tid; j<BB*KK*7; j+=256) s_gt[j] = gt[j];
  for (int j=tid; j<AA*6; j+=256) s_anc[j] = anc[j];
  if (tid<3) s_im[tid] = imi[tid];
  if (tid==0) s_w = ((const float*)ws)[O_W];
  __syncthreads();
  int t = blockIdx.x*256 + tid;
  if (t >= OUT0N) return;
  int d = t % DD; int r1=t/DD; int w=r1%WW; int r2=r1/WW;
  int h = r2 % HH; int r3=r2/HH; int a=r3%AA; int b=r3/AA;
  float L = out0c[t];
  int am = ((const int*)ws)[O_ARGMAX + t];
  float fx=w*STRIDE_F, fy=h*STRIDE_F, fz=d*STRIDE_F;
  float ax1=s_anc[a*6+0]+fx, ay1=s_anc[a*6+1]+fy, ax2=s_anc[a*6+2]+fx;
  float ay2=s_anc[a*6+3]+fy, az1=s_anc[a*6+4]+fz, az2=s_anc[a*6+5]+fz;
  bool inside = (ax1>=0.f)&&(ay1>=0.f)&&(az1>=0.f)&&
                (ax2<s_im[1])&&(ay2<s_im[0])&&(az2<s_im[2]);
  float bt[6] = {0.f,0.f,0.f,0.f,0.f,0.f};
  if (inside){
    const float* g = &s_gt[(b*KK + am)*7];
    float ew=ax2-ax1+1.f, eh=ay2-ay1+1.f, ed=az2-az1+1.f;
    float ecx=ax1+0.5f*(ew-1.f), ecy=ay1+0.5f*(eh-1.f), ecz=az1+0.5f*(ed-1.f);
    float gw=g[2]-g[0]+1.f, gh=g[3]-g[1]+1.f, gd=g[5]-g[4]+1.f;
    float gcx=g[0]+0.5f*(gw-1.f), gcy=g[1]+0.5f*(gh-1.f), gcz=g[4]+0.5f*(gd-1.f);
    bt[0]=(gcx-ecx)/ew; bt[1]=(gcy-ecy)/eh; bt[2]=(gcz-ecz)/ed;
    bt[3]=logf(gw/ew);  bt[4]=logf(gh/eh);  bt[5]=logf(gd/ed);
  }
  float iwv = (L==1.0f) ? 1.0f : 0.0f;
  float owv = (L==1.0f || L==0.0f) ? s_w : 0.0f;
  int sp = (h*WW + w)*DD + d;
  float* out1 = out + OUT0N;
  float* out2 = out1 + BB*CH*SPAT;
  float* out3 = out2 + BB*CH*SPAT;
  int basech = (b*CH + a*6)*SPAT + sp;
  #pragma unroll
  for (int c=0; c<6; c++){
    int off = basech + c*SPAT;
    out1[off] = bt[c];
    out2[off] = iwv;
    out3[off] = owv;
  }
}

extern "C" void kernel_launch(void* const* d_in, const int* in_sizes, int n_in,
                              void* d_out, int out_size, void* d_ws, size_t ws_size,
                              hipStream_t stream) {
  (void)in_sizes; (void)n_in; (void)out_size; (void)ws_size;
  const float* gt  = (const float*)d_in[1];
  const float* imi = (const float*)d_in[2];
  const float* anc = (const float*)d_in[4];
  const float* rfg = (const float*)d_in[5];
  const float* rbg = (const float*)d_in[6];
  float* out = (float*)d_out;
  unsigned* ws = (unsigned*)d_ws;
  int nb = (OUT0N + 255)/256;  // 3888
  k_init   <<<dim3((4*NB+255)/256), dim3(256), 0, stream>>>(ws);
  k_gtmax  <<<dim3(GM_BLK, BB), dim3(256), 0, stream>>>(gt, anc, imi, ws);
  k_label  <<<dim3(nb), dim3(256), 0, stream>>>(gt, anc, imi, rfg, rbg, out, ws);
  k_cuts   <<<dim3(4), dim3(256), 0, stream>>>(ws);
  k_apply  <<<dim3(nb), dim3(256), 0, stream>>>(rfg, rbg, out, ws);
  k_resolve<<<dim3(4), dim3(256), 0, stream>>>(rfg, rbg, out, ws);
  k_out    <<<dim3(nb), dim3(256), 0, stream>>>(gt, anc, imi, out, out, ws);
}

// Round 2
// 184.438 us; speedup vs baseline: 1.0262x; 1.0262x over previous
//
#include <hip/hip_runtime.h>
#include <math.h>

// Problem constants (setup_inputs is fixed)
#define BB 2
#define HH 48
#define WW 48
#define DD 24
#define KK 20
#define AA 9
#define TOTAL (HH*WW*DD*AA)   // 497664 anchors per batch (natural i = ((h*W+w)*D+d)*A+a)
#define SPAT (HH*WW*DD)       // 55296
#define OUT0N (BB*TOTAL)      // 995328, output-0 order t = (((b*A+a)*H+h)*W+w)*D+d
#define CH 54                 // 6*A channels for outputs 1..3
#define NB 4096               // rand-value histogram buckets
#define CAPB 256              // member-list capacity per bucket (mean ~120, +12 sigma)
#define FG_QUOTA 128
#define RPN_B 256
#define STRIDE_F 16.0f

// Workspace layout (4-byte words). ~21 MB total (ws is ~300 MB).
#define O_REC    0                        // OUT0N packed records
#define O_GTMAX  (OUT0N)                  // B*K encoded float maxima (memset-0 init)
#define O_HIST   (O_GTMAX + BB*KK)        // 4 flavors (fg b0, fg b1, bg b0, bg b1) * NB
#define O_CUT    (O_HIST + 4*NB)          // 4 flavors * 4 ints: cutb, rank_base, quota, count
#define O_W      (O_CUT + 16)             // scalar weight 1/num_examples (batch B-1)
#define O_LIST   (O_W + 1)                // 4*NB*CAPB member indices

// Monotone float<->uint encoding so unsigned atomicMax == float max (exact).
// All stored values are >= enc(-1.0f)=0x407FFFFF > 0, so memset-0 init is safe.
__device__ __forceinline__ unsigned enc_f(float f){
  unsigned u = __float_as_uint(f);
  return (u & 0x80000000u) ? ~u : (u | 0x80000000u);
}
__device__ __forceinline__ float dec_f(unsigned u){
  return (u & 0x80000000u) ? __uint_as_float(u & 0x7FFFFFFFu) : __uint_as_float(~u);
}
#define ENC_NEG1 0x407FFFFFu  // enc(-1.0f)

// IoU exactly as reference. fp contract OFF so the two call sites (k_gtmax,
// k_label) produce bit-identical values -> tie detection (==) is exact.
__device__ __forceinline__ float iou6(float ax1,float ay1,float ax2,float ay2,
                                      float az1,float az2, const float* g){
  #pragma clang fp contract(off)
  float aw = ax2-ax1+1.0f, ah = ay2-ay1+1.0f, ad = az2-az1+1.0f;
  float a_area = aw*ah*ad;
  float gw = g[2]-g[0]+1.0f, gh = g[3]-g[1]+1.0f, gd = g[5]-g[4]+1.0f;
  float g_area = gw*gh*gd;
  float iw = fminf(ax2,g[2]) - fmaxf(ax1,g[0]) + 1.0f; iw = fmaxf(iw,0.0f);
  float ih = fminf(ay2,g[3]) - fmaxf(ay1,g[1]) + 1.0f; ih = fmaxf(ih,0.0f);
  float id = fminf(az2,g[5]) - fmaxf(az1,g[4]) + 1.0f; id = fmaxf(id,0.0f);
  float inter = iw*ih*id;
  float ov = inter / (a_area + g_area - inter);
  if (gw==1.0f && gh==1.0f && gd==1.0f) ov = 0.0f;       // gt_zero mask
  if (aw==1.0f && ah==1.0f && ad==1.0f) ov = -1.0f;      // a_zero mask
  return ov;
}

// K1: per-gt max overlap (inside-masked). 8 anchors/thread, 20 running maxima
// in registers; wave shuffle-reduce; LDS atomic; one global atomicMax per
// (block,k). 16 blocks (y==0) also zero the 4*NB histogram for K2.
#define GM_G 8
#define GM_BLK 243  // TOTAL / (256*GM_G)
__global__ void __launch_bounds__(256) k_gtmax(const float* __restrict__ gt,
    const float* __restrict__ anc, const float* __restrict__ imi,
    unsigned* __restrict__ ws){
  __shared__ float s_gt[KK*7];
  __shared__ float s_anc[AA*6];
  __shared__ float s_im[3];
  __shared__ unsigned s_max[KK];
  int tid = threadIdx.x;
  int b = blockIdx.y;
  if (blockIdx.y == 0 && blockIdx.x < 16){    // fold k_init: zero hist
    int base = blockIdx.x*256 + tid;          // 4096 threads cover 4*NB
    #pragma unroll
    for (int j=0;j<4;j++) ws[O_HIST + j*NB + base] = 0u;
  }
  for (int j=tid; j<KK*7; j+=256) s_gt[j] = gt[b*KK*7 + j];
  for (int j=tid; j<AA*6; j+=256) s_anc[j] = anc[j];
  if (tid<3) s_im[tid] = imi[tid];
  if (tid<KK) s_max[tid] = ENC_NEG1;
  __syncthreads();
  float rmax[KK];
  #pragma unroll
  for (int k=0;k<KK;k++) rmax[k] = -1.0f;
  int i0 = blockIdx.x*256 + tid;
  for (int g=0; g<GM_G; g++){
    int i = i0 + g*(GM_BLK*256);
    int a = i % AA; int s = i / AA;
    int d = s % DD; int s2 = s / DD;
    int w = s2 % WW; int h = s2 / WW;
    float fx = w*STRIDE_F, fy = h*STRIDE_F, fz = d*STRIDE_F;
    float ax1=s_anc[a*6+0]+fx, ay1=s_anc[a*6+1]+fy, ax2=s_anc[a*6+2]+fx;
    float ay2=s_anc[a*6+3]+fy, az1=s_anc[a*6+4]+fz, az2=s_anc[a*6+5]+fz;
    bool inside = (ax1>=0.f)&&(ay1>=0.f)&&(az1>=0.f)&&
                  (ax2<s_im[1])&&(ay2<s_im[0])&&(az2<s_im[2]);
    if (!inside) continue;  // outside -> ov_m = -1 == init, no contribution
    #pragma unroll
    for (int k=0;k<KK;k++)
      rmax[k] = fmaxf(rmax[k], iou6(ax1,ay1,ax2,ay2,az1,az2, &s_gt[k*7]));
  }
  #pragma unroll
  for (int k=0;k<KK;k++){
    float v = rmax[k];
    for (int off=32; off>0; off>>=1) v = fmaxf(v, __shfl_down(v, off, 64));
    if ((tid & 63) == 0) atomicMax(&s_max[k], enc_f(v));
  }
  __syncthreads();
  if (tid < KK) atomicMax(&ws[O_GTMAX + b*KK + tid], s_max[tid]);
}

// K2: labels (pre-sampling) packed with argmax + rand bucket into one 32-bit
// record per anchor (t-order); candidates histogrammed AND appended to the
// per-bucket member list (same atomicAdd gives the slot).
__global__ void __launch_bounds__(256) k_label(const float* __restrict__ gt,
    const float* __restrict__ anc, const float* __restrict__ imi,
    const float* __restrict__ rfg, const float* __restrict__ rbg,
    unsigned* __restrict__ ws){
  __shared__ float s_gt[BB*KK*7];
  __shared__ float s_anc[AA*6];
  __shared__ float s_im[3];
  __shared__ float s_gm[BB*KK];
  int tid = threadIdx.x;
  for (int j=tid; j<BB*KK*7; j+=256) s_gt[j] = gt[j];
  for (int j=tid; j<AA*6; j+=256) s_anc[j] = anc[j];
  if (tid<3) s_im[tid] = imi[tid];
  if (tid<BB*KK){ float g = dec_f(ws[O_GTMAX+tid]); if (g==0.0f) g = 1e-5f; s_gm[tid]=g; }
  __syncthreads();
  int t = blockIdx.x*256 + tid;
  int d = t % DD; int r1 = t/DD;
  int w = r1 % WW; int r2 = r1/WW;
  int h = r2 % HH; int r3 = r2/HH;
  int a = r3 % AA; int b = r3/AA;
  int i = ((h*WW+w)*DD + d)*AA + a;       // natural anchor index (rand arrays)
  float fx=w*STRIDE_F, fy=h*STRIDE_F, fz=d*STRIDE_F;
  float ax1=s_anc[a*6+0]+fx, ay1=s_anc[a*6+1]+fy, ax2=s_anc[a*6+2]+fx;
  float ay2=s_anc[a*6+3]+fy, az1=s_anc[a*6+4]+fz, az2=s_anc[a*6+5]+fz;
  bool inside = (ax1>=0.f)&&(ay1>=0.f)&&(az1>=0.f)&&
                (ax2<s_im[1])&&(ay2<s_im[0])&&(az2<s_im[2]);
  float L = -1.0f;
  int am = 0;
  if (inside){
    float mv = -2.0f; bool tie = false;
    #pragma unroll
    for (int k=0;k<KK;k++){
      float ov = iou6(ax1,ay1,ax2,ay2,az1,az2, &s_gt[(b*KK+k)*7]);
      if (ov > mv){ mv = ov; am = k; }        // first-argmax (strict >)
      tie = tie || (ov == s_gm[b*KK+k]);
    }
    if (mv < 0.3f) L = 0.0f;
    if (tie)       L = 1.0f;
    if (mv >= 0.7f) L = 1.0f;
  }
  unsigned code = (L==1.0f) ? 2u : ((L==0.0f) ? 1u : 0u);
  unsigned bucket = 0;
  if (code){
    int fl = (code==1u ? 2 : 0) + b;
    const float* ra = (code==1u) ? rbg : rfg;
    float r = ra[b*TOTAL + i];
    bucket = (unsigned)min(NB-1, (int)(r*(float)NB));
    unsigned pos = atomicAdd(&ws[O_HIST + fl*NB + bucket], 1u);
    if (pos < CAPB) ((int*)ws)[O_LIST + ((fl*NB + (int)bucket)<<8) + pos] = i;
  }
  ws[O_REC + t] = code | ((unsigned)am<<2) | (bucket<<7);
}

// K3: one block per flavor: suffix-scan the histogram (descending value
// order) to find the bucket containing rank quota-1. Block 3 also computes w.
__global__ void __launch_bounds__(256) k_cuts(unsigned* __restrict__ ws){
  int fl = blockIdx.x; int tid = threadIdx.x;
  int b = fl & 1; int isbg = fl >> 1;
  const int CHK = NB/256;  // 16
  __shared__ unsigned ps[256];
  __shared__ unsigned s_fg;
  if (tid == 0) s_fg = 0u;
  __syncthreads();
  unsigned part = 0;                 // own flavor, descending chunk
  int hi = NB - CHK*tid;
  for (int j = hi-CHK; j < hi; j++) part += ws[O_HIST + fl*NB + j];
  if (isbg){
    unsigned pf = 0;                 // fg count of this batch (for quota / w)
    for (int j = tid*CHK; j < (tid+1)*CHK; j++) pf += ws[O_HIST + b*NB + j];
    atomicAdd(&s_fg, pf);
  }
  ps[tid] = part;
  __syncthreads();
  for (int off=1; off<256; off<<=1){
    unsigned v = (tid>=off) ? ps[tid-off] : 0u;
    __syncthreads();
    ps[tid] += v;
    __syncthreads();
  }
  unsigned N = ps[255];
  unsigned excl = ps[tid] - part;    // candidates in buckets above my chunk
  unsigned F = isbg ? s_fg : N;
  int quota = isbg ? (RPN_B - (int)min(F, (unsigned)FG_QUOTA)) : FG_QUOTA;
  if (fl == 3 && tid == 0){          // w uses batch B-1 counts only
    int fgk = min((int)F, FG_QUOTA);
    int bgk = min((int)N, RPN_B - fgk);
    ((float*)ws)[O_W] = 1.0f / (float)(fgk + bgk);
  }
  int* cut = (int*)&ws[O_CUT + fl*4];
  if ((int)N <= quota){
    if (tid==0){ cut[0] = -1; cut[1] = 0; cut[2] = quota; cut[3] = 0; }
    return;
  }
  unsigned cum = excl;
  for (int bk = hi-1; bk >= hi-CHK; bk--){
    unsigned c = ws[O_HIST + fl*NB + bk];
    if (c > 0u && (unsigned)(quota-1) >= cum && (unsigned)(quota-1) < cum + c){
      cut[0] = bk; cut[1] = (int)cum; cut[2] = quota; cut[3] = (int)c;
    }
    cum += c;
  }
}

// K4: fused apply+resolve+outputs. Decodes the record, finalizes the label
// (cut-bucket threads rank themselves by scanning the ~120-member list:
// descending value, ascending natural index — == jnp stable argsort of -p),
// writes labels, bbox targets, inside/outside weights.
__global__ void __launch_bounds__(256) k_out(const float* __restrict__ gt,
    const float* __restrict__ anc, const float* __restrict__ imi,
    const float* __restrict__ rfg, const float* __restrict__ rbg,
    float* __restrict__ out, const unsigned* __restrict__ ws){
  __shared__ float s_gt[BB*KK*7];
  __shared__ float s_anc[AA*6];
  __shared__ float s_im[3];
  __shared__ float s_w;
  int tid = threadIdx.x;
  for (int j=tid; j<BB*KK*7; j+=256) s_gt[j] = gt[j];
  for (int j=tid; j<AA*6; j+=256) s_anc[j] = anc[j];
  if (tid<3) s_im[tid] = imi[tid];
  if (tid==0) s_w = ((const float*)ws)[O_W];
  __syncthreads();
  int t = blockIdx.x*256 + tid;
  int d = t % DD; int r1=t/DD; int w=r1%WW; int r2=r1/WW;
  int h = r2 % HH; int r3=r2/HH; int a=r3%AA; int b=r3/AA;
  unsigned rec = ws[O_REC + t];
  unsigned code = rec & 3u;
  int am = (int)((rec>>2) & 31u);
  int bucket = (int)((rec>>7) & 4095u);
  float L = (code==2u) ? 1.0f : ((code==1u) ? 0.0f : -1.0f);
  if (code){
    int isbg = (code==1u);
    int fl = isbg*2 + b;
    const int* cut = (const int*)&ws[O_CUT + fl*4];
    int cutb = cut[0];
    if (cutb >= 0){
      if (bucket < cutb) L = -1.0f;
      else if (bucket == cutb){
        int rank_base = cut[1], quota = cut[2];
        int n = min(cut[3], CAPB);
        int i = ((h*WW+w)*DD + d)*AA + a;
        const float* ra = isbg ? rbg : rfg;
        float ri = ra[b*TOTAL + i];
        const int* lst = (const int*)ws + O_LIST + ((fl*NB + cutb)<<8);
        int cnt = 0;
        for (int e=0; e<n; e++){
          int j = lst[e];
          float rj = ra[b*TOTAL + j];
          cnt += (rj > ri) || (rj == ri && j < i);   // j==i adds 0
        }
        if (rank_base + cnt >= quota) L = -1.0f;
      }
    }
  }
  float fx=w*STRIDE_F, fy=h*STRIDE_F, fz=d*STRIDE_F;
  float ax1=s_anc[a*6+0]+fx, ay1=s_anc[a*6+1]+fy, ax2=s_anc[a*6+2]+fx;
  float ay2=s_anc[a*6+3]+fy, az1=s_anc[a*6+4]+fz, az2=s_anc[a*6+5]+fz;
  bool inside = (ax1>=0.f)&&(ay1>=0.f)&&(az1>=0.f)&&
                (ax2<s_im[1])&&(ay2<s_im[0])&&(az2<s_im[2]);
  float bt[6] = {0.f,0.f,0.f,0.f,0.f,0.f};
  if (inside){
    const float* g = &s_gt[(b*KK + am)*7];
    float ew=ax2-ax1+1.f, eh=ay2-ay1+1.f, ed=az2-az1+1.f;
    float ecx=ax1+0.5f*(ew-1.f), ecy=ay1+0.5f*(eh-1.f), ecz=az1+0.5f*(ed-1.f);
    float gw=g[2]-g[0]+1.f, gh=g[3]-g[1]+1.f, gd=g[5]-g[4]+1.f;
    float gcx=g[0]+0.5f*(gw-1.f), gcy=g[1]+0.5f*(gh-1.f), gcz=g[4]+0.5f*(gd-1.f);
    bt[0]=(gcx-ecx)/ew; bt[1]=(gcy-ecy)/eh; bt[2]=(gcz-ecz)/ed;
    bt[3]=logf(gw/ew);  bt[4]=logf(gh/eh);  bt[5]=logf(gd/ed);
  }
  out[t] = L;
  float iwv = (L==1.0f) ? 1.0f : 0.0f;
  float owv = (L==1.0f || L==0.0f) ? s_w : 0.0f;
  int sp = (h*WW + w)*DD + d;
  float* out1 = out + OUT0N;
  float* out2 = out1 + BB*CH*SPAT;
  float* out3 = out2 + BB*CH*SPAT;
  int basech = (b*CH + a*6)*SPAT + sp;
  #pragma unroll
  for (int c=0; c<6; c++){
    int off = basech + c*SPAT;
    out1[off] = bt[c];
    out2[off] = iwv;
    out3[off] = owv;
  }
}

extern "C" void kernel_launch(void* const* d_in, const int* in_sizes, int n_in,
                              void* d_out, int out_size, void* d_ws, size_t ws_size,
                              hipStream_t stream) {
  (void)in_sizes; (void)n_in; (void)out_size; (void)ws_size;
  const float* gt  = (const float*)d_in[1];
  const float* imi = (const float*)d_in[2];
  const float* anc = (const float*)d_in[4];
  const float* rfg = (const float*)d_in[5];
  const float* rbg = (const float*)d_in[6];
  float* out = (float*)d_out;
  unsigned* ws = (unsigned*)d_ws;
  int nb = (OUT0N + 255)/256;  // 3888
  hipMemsetAsync((char*)d_ws + (size_t)O_GTMAX*4, 0, BB*KK*4, stream);
  k_gtmax <<<dim3(GM_BLK, BB), dim3(256), 0, stream>>>(gt, anc, imi, ws);
  k_label <<<dim3(nb), dim3(256), 0, stream>>>(gt, anc, imi, rfg, rbg, ws);
  k_cuts  <<<dim3(4), dim3(256), 0, stream>>>(ws);
  k_out   <<<dim3(nb), dim3(256), 0, stream>>>(gt, anc, imi, rfg, rbg, out, ws);
}